// Round 1
// baseline (92.387 us; speedup 1.0000x reference)
//
#include <hip/hip_runtime.h>

// TensorFusion: out = relu(relu(fused @ W1 + b1) @ W2 + b2) @ W3 + b3
// fused[b, i*1024+j*32+k] = z0[b,i]*z1[b,j]*z2[b,k], z* = [x*, 1]
// B=256, D=31 (+bias col -> 32), FUSED=32768, H1=1024, H2=256, NCLS=4

typedef _Float16 half8 __attribute__((ext_vector_type(8)));
typedef float f32x4 __attribute__((ext_vector_type(4)));

#define KSPLIT 16
#define KCHUNK 2048            // 32768 / KSPLIT
#define STEPS  64              // KCHUNK / 32  (one (i,j) pair per step)

// ---------------------------------------------------------------------------
// K1: partial[ks][b][h] = sum over K-chunk of fused[b,k] * W1[k,h]
// grid 256 = 16 ntiles * 16 ksplit, block 512 (8 waves: 4 in M x 2 in N)
// block tile: M=256 (all b) x N=64; wave tile 64x32; MFMA 16x16x32 f16
// ---------------------------------------------------------------------------
__global__ __launch_bounds__(512, 2) void k1_gemm(
    const float* __restrict__ x0, const float* __restrict__ x1,
    const float* __restrict__ x2, const float* __restrict__ W1,
    float* __restrict__ partial)
{
    __shared__ _Float16 z01L[STEPS * 256];   // 32 KB: z0[b,i]*z1[b,j] per pair

    const int tid = threadIdx.x;
    const int nt  = blockIdx.x & 15;
    const int ks  = blockIdx.x >> 4;

    // Precompute z01 for this block's 64 (i,j) pairs
    for (int idx = tid; idx < STEPS * 256; idx += 512) {
        int pp = idx >> 8, b = idx & 255;
        int p  = ks * STEPS + pp;          // global pair index
        int i  = p >> 5, j = p & 31;
        float v0 = (i < 31) ? x0[b * 31 + i] : 1.0f;
        float v1 = (j < 31) ? x1[b * 31 + j] : 1.0f;
        z01L[pp * 256 + b] = (_Float16)(v0 * v1);
    }
    __syncthreads();

    const int lane  = tid & 63;
    const int wave  = tid >> 6;       // 0..7
    const int wm    = wave >> 1;      // 0..3 -> m base = wm*64
    const int wn    = wave & 1;       // 0..1 -> n offset wn*32
    const int row16 = lane & 15;
    const int kgrp  = lane >> 4;      // 0..3

    // z2 fragment per M-sub, f16 (k' = kgrp*8 + e matches MFMA A k-mapping)
    half8 z2v[4];
#pragma unroll
    for (int ms = 0; ms < 4; ++ms) {
        int b = wm * 64 + ms * 16 + row16;
#pragma unroll
        for (int e = 0; e < 8; ++e) {
            int kp = kgrp * 8 + e;
            float v = (kp < 31) ? x2[b * 31 + kp] : 1.0f;
            z2v[ms][e] = (_Float16)v;
        }
    }

    const int ncol0 = nt * 64 + wn * 32 + row16;   // B col for ns=0 (ns=1 -> +16)

    f32x4 acc[4][2] = {};

    // Prologue: load B fragments for step 0 (f32, converted per step)
    float bcur[16];
    {
        int rb = ks * KCHUNK + kgrp * 8;
#pragma unroll
        for (int ns = 0; ns < 2; ++ns)
#pragma unroll
            for (int e = 0; e < 8; ++e)
                bcur[ns * 8 + e] = W1[(rb + e) * 1024 + ncol0 + ns * 16];
    }

#pragma unroll 2
    for (int step = 0; step < STEPS; ++step) {
        float bnxt[16];
        const bool has_next = (step + 1 < STEPS);
        if (has_next) {
            int rbn = ks * KCHUNK + (step + 1) * 32 + kgrp * 8;
#pragma unroll
            for (int ns = 0; ns < 2; ++ns)
#pragma unroll
                for (int e = 0; e < 8; ++e)
                    bnxt[ns * 8 + e] = W1[(rbn + e) * 1024 + ncol0 + ns * 16];
        }

        // Convert current B to f16 fragments
        half8 bh0, bh1;
#pragma unroll
        for (int e = 0; e < 8; ++e) {
            bh0[e] = (_Float16)bcur[e];
            bh1[e] = (_Float16)bcur[8 + e];
        }

        // A fragments on the fly + MFMA
#pragma unroll
        for (int ms = 0; ms < 4; ++ms) {
            _Float16 zz = z01L[step * 256 + wm * 64 + ms * 16 + row16];
            half8 a = z2v[ms] * zz;
            acc[ms][0] = __builtin_amdgcn_mfma_f32_16x16x32_f16(a, bh0, acc[ms][0], 0, 0, 0);
            acc[ms][1] = __builtin_amdgcn_mfma_f32_16x16x32_f16(a, bh1, acc[ms][1], 0, 0, 0);
        }

        if (has_next) {
#pragma unroll
            for (int q = 0; q < 16; ++q) bcur[q] = bnxt[q];
        }
    }

    // Epilogue: D layout col = lane&15, row = (lane>>4)*4 + r
    float* pout = partial + (size_t)ks * (256 * 1024);
#pragma unroll
    for (int ms = 0; ms < 4; ++ms)
#pragma unroll
        for (int ns = 0; ns < 2; ++ns)
#pragma unroll
            for (int r = 0; r < 4; ++r) {
                int brow = wm * 64 + ms * 16 + kgrp * 4 + r;
                int ncol = nt * 64 + wn * 32 + ns * 16 + row16;
                pout[brow * 1024 + ncol] = acc[ms][ns][r];
            }
}

// ---------------------------------------------------------------------------
// K2: h1[e] = relu(sum_s partial[s][e] + b1[e%1024]); h1 aliases partial[0]
// ---------------------------------------------------------------------------
__global__ __launch_bounds__(256) void k2_reduce(
    const float* __restrict__ partial, const float* __restrict__ b1,
    float* __restrict__ h1)
{
    int e = blockIdx.x * 256 + threadIdx.x;   // grid 1024 -> 262144 elements
    float s = 0.f;
#pragma unroll
    for (int sp = 0; sp < KSPLIT; ++sp) s += partial[sp * 262144 + e];
    s += b1[e & 1023];
    h1[e] = fmaxf(s, 0.f);
}

// ---------------------------------------------------------------------------
// K3: layer 2 partials, M=256 K=1024 N=256; Mtile=32 Ntile=64 Ksplit=8
// grid (8,4,8), block 256
// ---------------------------------------------------------------------------
__global__ __launch_bounds__(256) void k3_layer2(
    const float* __restrict__ h1, const float* __restrict__ W2,
    float* __restrict__ p2)
{
    __shared__ float h1t[32 * 129];
    __shared__ float w2t[128 * 65];
    const int tid = threadIdx.x;
    const int m0 = blockIdx.x * 32, n0 = blockIdx.y * 64, k0 = blockIdx.z * 128;

    for (int idx = tid; idx < 32 * 128; idx += 256) {
        int m = idx >> 7, kk = idx & 127;
        h1t[m * 129 + kk] = h1[(m0 + m) * 1024 + k0 + kk];
    }
    for (int idx = tid; idx < 128 * 64; idx += 256) {
        int kk = idx >> 6, n = idx & 63;
        w2t[kk * 65 + n] = W2[(k0 + kk) * 256 + n0 + n];
    }
    __syncthreads();

    const int tn = tid & 63, tm = tid >> 6;   // tm 0..3
    float acc[8] = {};
    for (int kk = 0; kk < 128; ++kk) {
        float w = w2t[kk * 65 + tn];
#pragma unroll
        for (int r = 0; r < 8; ++r)
            acc[r] += h1t[(tm * 8 + r) * 129 + kk] * w;
    }
#pragma unroll
    for (int r = 0; r < 8; ++r)
        p2[blockIdx.z * 65536 + (m0 + tm * 8 + r) * 256 + n0 + tn] = acc[r];
}

// ---------------------------------------------------------------------------
// K4: h2 = relu(sum_s p2[s] + b2); out = h2 @ W3 + b3. One block per sample.
// ---------------------------------------------------------------------------
__global__ __launch_bounds__(256) void k4_final(
    const float* __restrict__ p2, const float* __restrict__ b2,
    const float* __restrict__ W3, const float* __restrict__ b3,
    float* __restrict__ out)
{
    __shared__ float pL[256 * 5];
    const int b = blockIdx.x, n = threadIdx.x;
    float s = 0.f;
#pragma unroll
    for (int sp = 0; sp < 8; ++sp) s += p2[sp * 65536 + b * 256 + n];
    float h2 = fmaxf(s + b2[n], 0.f);
#pragma unroll
    for (int c = 0; c < 4; ++c) pL[n * 5 + c] = h2 * W3[n * 4 + c];
    __syncthreads();

    const int lane = n & 63, w = n >> 6;      // wave w handles class c=w
    float v = pL[lane * 5 + w] + pL[(lane + 64) * 5 + w] +
              pL[(lane + 128) * 5 + w] + pL[(lane + 192) * 5 + w];
#pragma unroll
    for (int off = 32; off > 0; off >>= 1) v += __shfl_down(v, off);
    if (lane == 0) out[b * 4 + w] = v + b3[w];
}

extern "C" void kernel_launch(void* const* d_in, const int* in_sizes, int n_in,
                              void* d_out, int out_size, void* d_ws, size_t ws_size,
                              hipStream_t stream)
{
    (void)in_sizes; (void)n_in; (void)out_size; (void)ws_size;
    const float* x0 = (const float*)d_in[0];
    const float* x1 = (const float*)d_in[1];
    const float* x2 = (const float*)d_in[2];
    const float* W1 = (const float*)d_in[3];
    const float* b1 = (const float*)d_in[4];
    const float* W2 = (const float*)d_in[5];
    const float* b2 = (const float*)d_in[6];
    const float* W3 = (const float*)d_in[7];
    const float* b3 = (const float*)d_in[8];
    float* out = (float*)d_out;
    float* ws  = (float*)d_ws;

    // ws layout (floats): partial[16][262144] = 16.8 MB.
    // h1 (262144) aliases partial[0] (safe: k2 thread reads before writing its
    // own element); p2[8][65536] aliases partial[1..2] (dead after k2).
    float* partial = ws;
    float* h1 = ws;
    float* p2 = ws + 262144;

    k1_gemm  <<<dim3(256),     dim3(512), 0, stream>>>(x0, x1, x2, W1, partial);
    k2_reduce<<<dim3(1024),    dim3(256), 0, stream>>>(partial, b1, h1);
    k3_layer2<<<dim3(8, 4, 8), dim3(256), 0, stream>>>(h1, W2, p2);
    k4_final <<<dim3(256),     dim3(256), 0, stream>>>(p2, b2, W3, b3, out);
}

// Round 2
// 86.386 us; speedup vs baseline: 1.0695x; 1.0695x over previous
//
#include <hip/hip_runtime.h>

// TensorFusion: out = relu(relu(fused @ W1 + b1) @ W2 + b2) @ W3 + b3
// fused[b, i*1024+j*32+k] = z0[b,i]*z1[b,j]*z2[b,k], z* = [x*, 1]
// B=256, D=31 (+1 bias col -> 32), FUSED=32768, H1=1024, H2=256, NCLS=4

typedef _Float16 half8 __attribute__((ext_vector_type(8)));
typedef _Float16 half4 __attribute__((ext_vector_type(4)));
typedef float f32x4 __attribute__((ext_vector_type(4)));

#define GLD_LDS16(gsrc, ldst)                                                  \
    __builtin_amdgcn_global_load_lds(                                          \
        (const __attribute__((address_space(1))) void*)(gsrc),                 \
        (__attribute__((address_space(3))) void*)(ldst), 16, 0, 0)

// ---------------------------------------------------------------------------
// K1: partial[ks][b][h] = sum over K-chunk of fused[b,k] * W1[k,h]
// grid = 32 ntiles * KS ksplit blocks, 256 threads (4 waves).
// Block tile: M=256 x N=32. Wave w: M rows [w*64, w*64+64), full N=32.
// Per K-step (32 k = one (i,j) pair): MFMA 16x16x32 f16, acc[4 ms][2 ns].
// W1 tile 32k x 32n f32 staged to LDS via global_load_lds dwordx4,
// 4 buffers, prefetch depth 2, counted vmcnt (never 0 in main loop).
// Source-column XOR swizzle (rule 21) -> 2-way LDS read conflicts (free).
// ---------------------------------------------------------------------------
template<int KS, typename PT>
__global__ __launch_bounds__(256, 4) void k1_gemm(
    const float* __restrict__ x0, const float* __restrict__ x1,
    const float* __restrict__ x2, const float* __restrict__ W1,
    PT* __restrict__ partial)
{
    constexpr int KCHUNK = 32768 / KS;
    constexpr int STEPS  = KCHUNK / 32;   // pairs per block
    constexpr int GRPS   = STEPS / 4;

    __shared__ float    tiles[4 * 1024];      // 4 bufs x (32k x 32n) f32 = 16KB
    __shared__ _Float16 z01L[GRPS][256][4];   // z0[b,i]*z1[b,j] per pair

    const int tid  = threadIdx.x;
    const int bid  = blockIdx.x;
    const int nt   = bid & 31;
    const int ks   = bid >> 5;
    const int lane = tid & 63;
    const int w    = tid >> 6;        // wave 0..3
    const int nl   = lane & 15;
    const int g    = lane >> 4;       // 0..3

    const int kbase = ks * KCHUNK;

    // Staging map: wave w covers tile rows [w*8, w*8+8), lane covers 4 dwords.
    const int srow = w * 8 + (lane >> 3);
    const int scol = ((lane & 7) * 4) ^ (w << 3);   // pre-swizzled source col

    // Issue prefetch of tiles 0,1 ASAP (overlaps with z01 precompute).
    {
        const float* s0 = W1 + (size_t)(kbase + srow) * 1024 + nt * 32 + scol;
        GLD_LDS16(s0,             &tiles[0 * 1024 + w * 256]);
        GLD_LDS16(s0 + 32 * 1024, &tiles[1 * 1024 + w * 256]);
    }

    // z01 table: thread b = tid handles all pairs of this K-chunk.
    {
        const int b = tid;
        const int Pbase = kbase >> 5;
        for (int p = 0; p < STEPS; ++p) {
            int P = Pbase + p;
            int i = P >> 5, j = P & 31;
            float v0 = (i < 31) ? x0[b * 31 + i] : 1.0f;
            float v1 = (j < 31) ? x1[b * 31 + j] : 1.0f;
            z01L[p >> 2][b][p & 3] = (_Float16)(v0 * v1);
        }
    }

    // z2 register fragments (A-operand k-axis), per M-sub.
    half8 z2v[4];
#pragma unroll
    for (int ms = 0; ms < 4; ++ms) {
        int b = w * 64 + ms * 16 + nl;
#pragma unroll
        for (int e = 0; e < 8; ++e) {
            int kp = g * 8 + e;
            z2v[ms][e] = (_Float16)((kp < 31) ? x2[b * 31 + kp] : 1.0f);
        }
    }

    __syncthreads();   // z01 ready (drains the 2 prefetch loads too - OK)

    const int nswz0 = nl ^ (g << 3);          // swizzled dword col, ns=0
    const int nswz1 = (16 + nl) ^ (g << 3);   // ns=1

    f32x4 acc[4][2] = {};
    half4 zq[4];

#define K1_BODY(TT, NISSUE, VMC)                                               \
    {                                                                          \
        const int t = grp * 4 + TT;                                            \
        if (NISSUE) {                                                          \
            const float* s = W1 + (size_t)(kbase + (t + 2) * 32 + srow) * 1024 \
                             + nt * 32 + scol;                                 \
            GLD_LDS16(s, &tiles[((TT + 2) & 3) * 1024 + w * 256]);             \
        }                                                                      \
        asm volatile("s_waitcnt vmcnt(" #VMC ")" ::: "memory");                \
        asm volatile("s_barrier" ::: "memory");                                \
        if (TT == 0) {                                                         \
            _Pragma("unroll")                                                  \
            for (int ms = 0; ms < 4; ++ms)                                     \
                zq[ms] = *(const half4*)&z01L[grp][w * 64 + ms * 16 + nl][0];  \
        }                                                                      \
        const float* tf = &tiles[TT * 1024];                                   \
        half8 bh0, bh1;                                                        \
        _Pragma("unroll")                                                      \
        for (int e = 0; e < 8; ++e) {                                          \
            bh0[e] = (_Float16)tf[(g * 8 + e) * 32 + nswz0];                   \
            bh1[e] = (_Float16)tf[(g * 8 + e) * 32 + nswz1];                   \
        }                                                                      \
        _Pragma("unroll")                                                      \
        for (int ms = 0; ms < 4; ++ms) {                                       \
            half8 a = z2v[ms] * zq[ms][TT];                                    \
            acc[ms][0] = __builtin_amdgcn_mfma_f32_16x16x32_f16(a, bh0, acc[ms][0], 0, 0, 0); \
            acc[ms][1] = __builtin_amdgcn_mfma_f32_16x16x32_f16(a, bh1, acc[ms][1], 0, 0, 0); \
        }                                                                      \
    }

    for (int grp = 0; grp < GRPS - 1; ++grp) {
        K1_BODY(0, 1, 2)
        K1_BODY(1, 1, 2)
        K1_BODY(2, 1, 2)
        K1_BODY(3, 1, 2)
    }
    {
        const int grp = GRPS - 1;
        K1_BODY(0, 1, 2)
        K1_BODY(1, 1, 2)
        K1_BODY(2, 0, 1)
        K1_BODY(3, 0, 0)
    }
#undef K1_BODY

    // Epilogue: D layout col = lane&15, row = (lane>>4)*4 + r
    PT* pout = partial + (size_t)ks * (256 * 1024);
#pragma unroll
    for (int ms = 0; ms < 4; ++ms)
#pragma unroll
        for (int ns = 0; ns < 2; ++ns)
#pragma unroll
            for (int r = 0; r < 4; ++r) {
                int brow = w * 64 + ms * 16 + g * 4 + r;
                int ncol = nt * 32 + ns * 16 + nl;
                pout[brow * 1024 + ncol] = (PT)acc[ms][ns][r];
            }
}

// ---------------------------------------------------------------------------
// K2: h1[e] = relu(sum_s partial[s][e] + b1[e%1024])
// ---------------------------------------------------------------------------
template<int KS, typename PT>
__global__ __launch_bounds__(256) void k2_reduce(
    const PT* __restrict__ partial, const float* __restrict__ b1,
    float* __restrict__ h1)
{
    int e = blockIdx.x * 256 + threadIdx.x;   // grid 1024 -> 262144 elements
    float s = 0.f;
#pragma unroll
    for (int sp = 0; sp < KS; ++sp) s += (float)partial[(size_t)sp * 262144 + e];
    s += b1[e & 1023];
    h1[e] = fmaxf(s, 0.f);
}

// ---------------------------------------------------------------------------
// K3: layer 2 partials, M=256 K=1024 N=256; Mtile=32 Ntile=64 Ksplit=8
// ---------------------------------------------------------------------------
__global__ __launch_bounds__(256) void k3_layer2(
    const float* __restrict__ h1, const float* __restrict__ W2,
    float* __restrict__ p2)
{
    __shared__ float h1t[32 * 129];
    __shared__ float w2t[128 * 65];
    const int tid = threadIdx.x;
    const int m0 = blockIdx.x * 32, n0 = blockIdx.y * 64, k0 = blockIdx.z * 128;

    for (int idx = tid; idx < 32 * 128; idx += 256) {
        int m = idx >> 7, kk = idx & 127;
        h1t[m * 129 + kk] = h1[(m0 + m) * 1024 + k0 + kk];
    }
    for (int idx = tid; idx < 128 * 64; idx += 256) {
        int kk = idx >> 6, n = idx & 63;
        w2t[kk * 65 + n] = W2[(k0 + kk) * 256 + n0 + n];
    }
    __syncthreads();

    const int tn = tid & 63, tm = tid >> 6;   // tm 0..3
    float acc[8] = {};
    for (int kk = 0; kk < 128; ++kk) {
        float w = w2t[kk * 65 + tn];
#pragma unroll
        for (int r = 0; r < 8; ++r)
            acc[r] += h1t[(tm * 8 + r) * 129 + kk] * w;
    }
#pragma unroll
    for (int r = 0; r < 8; ++r)
        p2[blockIdx.z * 65536 + (m0 + tm * 8 + r) * 256 + n0 + tn] = acc[r];
}

// ---------------------------------------------------------------------------
// K4: h2 = relu(sum_s p2[s] + b2); out = h2 @ W3 + b3. One block per sample.
// ---------------------------------------------------------------------------
__global__ __launch_bounds__(256) void k4_final(
    const float* __restrict__ p2, const float* __restrict__ b2,
    const float* __restrict__ W3, const float* __restrict__ b3,
    float* __restrict__ out)
{
    __shared__ float pL[256 * 5];
    const int b = blockIdx.x, n = threadIdx.x;
    float s = 0.f;
#pragma unroll
    for (int sp = 0; sp < 8; ++sp) s += p2[sp * 65536 + b * 256 + n];
    float h2 = fmaxf(s + b2[n], 0.f);
#pragma unroll
    for (int c = 0; c < 4; ++c) pL[n * 5 + c] = h2 * W3[n * 4 + c];
    __syncthreads();

    const int lane = n & 63, w = n >> 6;      // wave w handles class c=w
    float v = pL[lane * 5 + w] + pL[(lane + 64) * 5 + w] +
              pL[(lane + 128) * 5 + w] + pL[(lane + 192) * 5 + w];
#pragma unroll
    for (int off = 32; off > 0; off >>= 1) v += __shfl_down(v, off);
    if (lane == 0) out[b * 4 + w] = v + b3[w];
}

extern "C" void kernel_launch(void* const* d_in, const int* in_sizes, int n_in,
                              void* d_out, int out_size, void* d_ws, size_t ws_size,
                              hipStream_t stream)
{
    (void)in_sizes; (void)n_in; (void)out_size;
    const float* x0 = (const float*)d_in[0];
    const float* x1 = (const float*)d_in[1];
    const float* x2 = (const float*)d_in[2];
    const float* W1 = (const float*)d_in[3];
    const float* b1 = (const float*)d_in[4];
    const float* W2 = (const float*)d_in[5];
    const float* b2 = (const float*)d_in[6];
    const float* W3 = (const float*)d_in[7];
    const float* b3 = (const float*)d_in[8];
    float* out = (float*)d_out;
    float* ws  = (float*)d_ws;

    const size_t needA = 32ull * 262144 * 4;                        // 33.55 MB
    const size_t needB = 32ull * 262144 * 2 + 262144ull * 4;        // 17.83 MB

    if (ws_size >= needA) {
        // f32 partials; h1 aliases partial[0] (each k2 thread reads its own
        // element before overwriting it); p2 aliases partial[1] (dead).
        float* partial = ws;
        float* h1 = ws;
        float* p2 = ws + 262144;
        k1_gemm<32, float><<<dim3(1024), dim3(256), 0, stream>>>(x0, x1, x2, W1, partial);
        k2_reduce<32, float><<<dim3(1024), dim3(256), 0, stream>>>(partial, b1, h1);
        k3_layer2<<<dim3(8, 4, 8), dim3(256), 0, stream>>>(h1, W2, p2);
        k4_final <<<dim3(256),     dim3(256), 0, stream>>>(p2, b2, W3, b3, out);
    } else if (ws_size >= needB) {
        // f16 partials; h1 placed after them; p2 aliases dead partial region.
        _Float16* partial = (_Float16*)d_ws;
        float* h1 = (float*)((char*)d_ws + 32ull * 262144 * 2);
        float* p2 = ws;
        k1_gemm<32, _Float16><<<dim3(1024), dim3(256), 0, stream>>>(x0, x1, x2, W1, partial);
        k2_reduce<32, _Float16><<<dim3(1024), dim3(256), 0, stream>>>(partial, b1, h1);
        k3_layer2<<<dim3(8, 4, 8), dim3(256), 0, stream>>>(h1, W2, p2);
        k4_final <<<dim3(256),     dim3(256), 0, stream>>>(p2, b2, W3, b3, out);
    } else {
        // minimal footprint fallback: KS=16, f16 partials (9.4 MB)
        _Float16* partial = (_Float16*)d_ws;
        float* h1 = (float*)((char*)d_ws + 16ull * 262144 * 2);
        float* p2 = ws;
        k1_gemm<16, _Float16><<<dim3(512), dim3(256), 0, stream>>>(x0, x1, x2, W1, partial);
        k2_reduce<16, _Float16><<<dim3(1024), dim3(256), 0, stream>>>(partial, b1, h1);
        k3_layer2<<<dim3(8, 4, 8), dim3(256), 0, stream>>>(h1, W2, p2);
        k4_final <<<dim3(256),     dim3(256), 0, stream>>>(p2, b2, W3, b3, out);
    }
}

// Round 3
// 51.585 us; speedup vs baseline: 1.7910x; 1.6746x over previous
//
#include <hip/hip_runtime.h>

// TensorFusion: out = relu(relu(fused @ W1 + b1) @ W2 + b2) @ W3 + b3
// fused[b, i*1024+j*32+k] = z0[b,i]*z1[b,j]*z2[b,k], z* = [x*, 1]
// B=256, D=31 (+1 bias col -> 32), FUSED=32768, H1=1024, H2=256, NCLS=4

typedef _Float16 half8 __attribute__((ext_vector_type(8)));
typedef _Float16 half4 __attribute__((ext_vector_type(4)));
typedef _Float16 half2 __attribute__((ext_vector_type(2)));
typedef float f32x4 __attribute__((ext_vector_type(4)));

#define KSPLIT 16

// ---------------------------------------------------------------------------
// K1: partial[ks][b][h] = sum over 2048-K-chunk of fused[b,k] * W1[k,h]
// grid = 32 ntiles * 16 ksplit = 512 blocks (2/CU), 512 threads (8 waves).
// Block tile M=256 x N=32; wave w: rows [w*32, w*32+32), full N.
// Pipeline: W1 f32 -> regs (4 tiles deep, 8 outstanding dwords/wave)
//   -> cvt f16 -> swizzled ds_write -> LDS [n][k] f16 ring of 4 bufs.
// Raw lgkmcnt(0)+s_barrier per step (no vmcnt drain); compiler emits
// counted vmcnt for the reg pipeline.
// ---------------------------------------------------------------------------
__global__ __launch_bounds__(512, 4) void k1_gemm(
    const float* __restrict__ x0, const float* __restrict__ x1,
    const float* __restrict__ x2, const float* __restrict__ W1,
    float* __restrict__ partial)
{
    constexpr int GRPS = 16;                 // 64 steps / 4
    __shared__ __align__(16) _Float16 z01L[GRPS][256][4];  // 32 KB
    __shared__ __align__(16) _Float16 tile[4][1024];       // 4 x 2KB, [n][k] swz

    const int tid  = threadIdx.x;
    const int nt   = blockIdx.x & 31;
    const int ks   = blockIdx.x >> 5;
    const int lane = tid & 63;
    const int w    = tid >> 6;        // wave 0..7
    const int nl   = lane & 15;
    const int g    = lane >> 4;       // 0..3
    const int kbase = ks * 2048;
    const int n0    = nt * 32;

    // ---- z01 table: pair p (0..63): i = ks*2 + (p>>5), j = p&31
    {
        const int b  = tid & 255;
        const int hf = tid >> 8;              // 0..1
        const int i  = ks * 2 + hf;
        const float v0 = (i < 31) ? x0[b * 31 + i] : 1.0f;
#pragma unroll
        for (int pp = 0; pp < 32; pp += 4) {
            half4 hv;
#pragma unroll
            for (int e = 0; e < 4; ++e) {
                int j = pp + e;
                float v1 = (j < 31) ? x1[b * 31 + j] : 1.0f;
                hv[e] = (_Float16)(v0 * v1);
            }
            *(half4*)&z01L[(hf * 32 + pp) >> 2][b][0] = hv;
        }
    }

    // ---- z2 register fragments (A-operand k-axis), 2 M-subtiles per wave
    half8 z2v[2];
#pragma unroll
    for (int ms = 0; ms < 2; ++ms) {
        int b = w * 32 + ms * 16 + nl;
#pragma unroll
        for (int e = 0; e < 8; ++e) {
            int kp = g * 8 + e;
            z2v[ms][e] = (_Float16)((kp < 31) ? x2[b * 31 + kp] : 1.0f);
        }
    }

    // ---- staging map: thread -> (col sn, k-pair sk2): 2 dwords per tile
    const int sn  = tid & 31;
    const int sk2 = tid >> 5;                 // 0..15 -> rows sk2*2, sk2*2+1
    const float* gsrc = W1 + (size_t)(kbase + sk2 * 2) * 1024 + n0 + sn;
    const int wswz = (((sn & 7) ^ (sn >> 3)) & 7) << 2;   // 4-f16 granule XOR
    const int woff = sn * 32 + ((sk2 * 2) ^ wswz);

    // ---- B-fragment read offsets (f16 idx), literal-indexed after unroll
    int roff[2][2];
#pragma unroll
    for (int ns = 0; ns < 2; ++ns) {
        int n = ns * 16 + nl;
        int s = (((n & 7) ^ (n >> 3)) & 7) << 2;
        roff[ns][0] = n * 32 + ((g * 8) ^ s);
        roff[ns][1] = n * 32 + ((g * 8 + 4) ^ s);
    }

    __syncthreads();   // z01L ready (full drain OK here, nothing in flight)

    // ---- prologue: fill 4-deep register pipeline (tiles 0..3)
    float rxv[4], ryv[4];
#pragma unroll
    for (int s = 0; s < 4; ++s) {
        rxv[s] = gsrc[(size_t)s * 32768];
        ryv[s] = gsrc[(size_t)s * 32768 + 1024];
    }
    {   // write tile 0 -> buf 0 (compiler inserts counted vmcnt)
        half2 hv; hv[0] = (_Float16)rxv[0]; hv[1] = (_Float16)ryv[0];
        *(half2*)&tile[0][woff] = hv;
    }
    asm volatile("s_waitcnt lgkmcnt(0)\n\ts_barrier" ::: "memory");

    f32x4 acc[2][2] = {};
    half4 zq0, zq1;

    // Per step T_: compute tile T_ (buf T_&3); issue loads tile T_+4 into
    // reg slot TT; cvt+write tile T_+1 (slot (TT+1)&3) AFTER the MFMAs so
    // the vmcnt wait overlaps compute; barrier gates next iter's reads.
#define ITER(T_, TT, ISSUE, WRITE)                                             \
    {                                                                          \
        if (ISSUE) {                                                           \
            rxv[TT] = gsrc[(size_t)((T_) + 4) * 32768];                        \
            ryv[TT] = gsrc[(size_t)((T_) + 4) * 32768 + 1024];                 \
        }                                                                      \
        if ((TT) == 0) {                                                       \
            zq0 = *(const half4*)&z01L[(T_) >> 2][w * 32 + nl][0];             \
            zq1 = *(const half4*)&z01L[(T_) >> 2][w * 32 + 16 + nl][0];        \
        }                                                                      \
        const _Float16* tb = &tile[(T_) & 3][0];                               \
        half4 lo0 = *(const half4*)&tb[roff[0][0]];                            \
        half4 hi0 = *(const half4*)&tb[roff[0][1]];                            \
        half4 lo1 = *(const half4*)&tb[roff[1][0]];                            \
        half4 hi1 = *(const half4*)&tb[roff[1][1]];                            \
        half8 bh0 = __builtin_shufflevector(lo0, hi0, 0,1,2,3,4,5,6,7);        \
        half8 bh1 = __builtin_shufflevector(lo1, hi1, 0,1,2,3,4,5,6,7);        \
        half8 a0 = z2v[0] * zq0[TT];                                           \
        half8 a1 = z2v[1] * zq1[TT];                                           \
        acc[0][0] = __builtin_amdgcn_mfma_f32_16x16x32_f16(a0, bh0, acc[0][0], 0, 0, 0); \
        acc[0][1] = __builtin_amdgcn_mfma_f32_16x16x32_f16(a0, bh1, acc[0][1], 0, 0, 0); \
        acc[1][0] = __builtin_amdgcn_mfma_f32_16x16x32_f16(a1, bh0, acc[1][0], 0, 0, 0); \
        acc[1][1] = __builtin_amdgcn_mfma_f32_16x16x32_f16(a1, bh1, acc[1][1], 0, 0, 0); \
        if (WRITE) {                                                           \
            half2 hv;                                                          \
            hv[0] = (_Float16)rxv[((TT) + 1) & 3];                             \
            hv[1] = (_Float16)ryv[((TT) + 1) & 3];                             \
            *(half2*)&tile[((T_) + 1) & 3][woff] = hv;                         \
        }                                                                      \
        asm volatile("s_waitcnt lgkmcnt(0)\n\ts_barrier" ::: "memory");        \
    }

    for (int grp = 0; grp < 15; ++grp) {
        const int t = grp * 4;
        ITER(t + 0, 0, 1, 1)
        ITER(t + 1, 1, 1, 1)
        ITER(t + 2, 2, 1, 1)
        ITER(t + 3, 3, 1, 1)
    }
    ITER(60, 0, 0, 1)
    ITER(61, 1, 0, 1)
    ITER(62, 2, 0, 1)
    ITER(63, 3, 0, 0)
#undef ITER

    // ---- epilogue: D layout col = lane&15, row = (lane>>4)*4 + r
    float* pout = partial + (size_t)ks * (256 * 1024);
#pragma unroll
    for (int ms = 0; ms < 2; ++ms)
#pragma unroll
        for (int ns = 0; ns < 2; ++ns)
#pragma unroll
            for (int r = 0; r < 4; ++r) {
                int brow = w * 32 + ms * 16 + g * 4 + r;
                int ncol = n0 + ns * 16 + nl;
                pout[brow * 1024 + ncol] = acc[ms][ns][r];
            }
}

// ---------------------------------------------------------------------------
// K2: h1[e] = relu(sum_s partial[s][e] + b1[e%1024]); h1 aliases partial[0]
// ---------------------------------------------------------------------------
__global__ __launch_bounds__(256) void k2_reduce(
    const float* __restrict__ partial, const float* __restrict__ b1,
    float* __restrict__ h1)
{
    int e = blockIdx.x * 256 + threadIdx.x;   // grid 1024 -> 262144 elements
    float s = 0.f;
#pragma unroll
    for (int sp = 0; sp < KSPLIT; ++sp) s += partial[(size_t)sp * 262144 + e];
    s += b1[e & 1023];
    h1[e] = fmaxf(s, 0.f);
}

// ---------------------------------------------------------------------------
// K3: layer 2 partials, M=256 K=1024 N=256; Mtile=32 Ntile=64 Ksplit=8
// ---------------------------------------------------------------------------
__global__ __launch_bounds__(256) void k3_layer2(
    const float* __restrict__ h1, const float* __restrict__ W2,
    float* __restrict__ p2)
{
    __shared__ float h1t[32 * 129];
    __shared__ float w2t[128 * 65];
    const int tid = threadIdx.x;
    const int m0 = blockIdx.x * 32, n0 = blockIdx.y * 64, k0 = blockIdx.z * 128;

    for (int idx = tid; idx < 32 * 128; idx += 256) {
        int m = idx >> 7, kk = idx & 127;
        h1t[m * 129 + kk] = h1[(m0 + m) * 1024 + k0 + kk];
    }
    for (int idx = tid; idx < 128 * 64; idx += 256) {
        int kk = idx >> 6, n = idx & 63;
        w2t[kk * 65 + n] = W2[(k0 + kk) * 256 + n0 + n];
    }
    __syncthreads();

    const int tn = tid & 63, tm = tid >> 6;   // tm 0..3
    float acc[8] = {};
    for (int kk = 0; kk < 128; ++kk) {
        float w = w2t[kk * 65 + tn];
#pragma unroll
        for (int r = 0; r < 8; ++r)
            acc[r] += h1t[(tm * 8 + r) * 129 + kk] * w;
    }
#pragma unroll
    for (int r = 0; r < 8; ++r)
        p2[blockIdx.z * 65536 + (m0 + tm * 8 + r) * 256 + n0 + tn] = acc[r];
}

// ---------------------------------------------------------------------------
// K4: h2 = relu(sum_s p2[s] + b2); out = h2 @ W3 + b3. One block per sample.
// ---------------------------------------------------------------------------
__global__ __launch_bounds__(256) void k4_final(
    const float* __restrict__ p2, const float* __restrict__ b2,
    const float* __restrict__ W3, const float* __restrict__ b3,
    float* __restrict__ out)
{
    __shared__ float pL[256 * 5];
    const int b = blockIdx.x, n = threadIdx.x;
    float s = 0.f;
#pragma unroll
    for (int sp = 0; sp < 8; ++sp) s += p2[sp * 65536 + b * 256 + n];
    float h2 = fmaxf(s + b2[n], 0.f);
#pragma unroll
    for (int c = 0; c < 4; ++c) pL[n * 5 + c] = h2 * W3[n * 4 + c];
    __syncthreads();

    const int lane = n & 63, w = n >> 6;      // wave w handles class c=w
    float v = pL[lane * 5 + w] + pL[(lane + 64) * 5 + w] +
              pL[(lane + 128) * 5 + w] + pL[(lane + 192) * 5 + w];
#pragma unroll
    for (int off = 32; off > 0; off >>= 1) v += __shfl_down(v, off);
    if (lane == 0) out[b * 4 + w] = v + b3[w];
}

extern "C" void kernel_launch(void* const* d_in, const int* in_sizes, int n_in,
                              void* d_out, int out_size, void* d_ws, size_t ws_size,
                              hipStream_t stream)
{
    (void)in_sizes; (void)n_in; (void)out_size; (void)ws_size;
    const float* x0 = (const float*)d_in[0];
    const float* x1 = (const float*)d_in[1];
    const float* x2 = (const float*)d_in[2];
    const float* W1 = (const float*)d_in[3];
    const float* b1 = (const float*)d_in[4];
    const float* W2 = (const float*)d_in[5];
    const float* b2 = (const float*)d_in[6];
    const float* W3 = (const float*)d_in[7];
    const float* b3 = (const float*)d_in[8];
    float* out = (float*)d_out;
    float* ws  = (float*)d_ws;

    // ws layout (floats): partial[16][262144] f32 = 16.8 MB (ws >= 33.5 MB
    // verified in R2). h1 aliases partial[0] (thread reads its own element
    // before overwriting); p2[8][65536] aliases partial[1] (dead after k2).
    float* partial = ws;
    float* h1 = ws;
    float* p2 = ws + 262144;

    k1_gemm  <<<dim3(512),     dim3(512), 0, stream>>>(x0, x1, x2, W1, partial);
    k2_reduce<<<dim3(1024),    dim3(256), 0, stream>>>(partial, b1, h1);
    k3_layer2<<<dim3(8, 4, 8), dim3(256), 0, stream>>>(h1, W2, p2);
    k4_final <<<dim3(256),     dim3(256), 0, stream>>>(p2, b2, W3, b3, out);
}